// Round 9
// baseline (172.576 us; speedup 1.0000x reference)
//
#include <hip/hip_runtime.h>
#include <stdint.h>

typedef unsigned short u16;
typedef short bf16x8 __attribute__((ext_vector_type(8)));
typedef float f32x4 __attribute__((ext_vector_type(4)));
typedef float f32x16 __attribute__((ext_vector_type(16)));

#define S_ 2048
#define HID_ 1024
#define H_ 16
#define D_ 64

#define LOG2E 1.4426950408889634f
#define SCALE_LOG2 0.18033688011112042f   /* 0.125 * log2(e) */
#define MAXC_LOG2 11.541560327111707f     /* 8 * log2(e) */

__device__ __forceinline__ u16 f2bf(float f) {
  uint32_t x = __builtin_bit_cast(uint32_t, f);
  uint32_t r = (x + 0x7fffu + ((x >> 16) & 1u)) >> 16;
  return (u16)r;
}
__device__ __forceinline__ uint32_t packbf2(float a, float b) {
  return (uint32_t)f2bf(a) | ((uint32_t)f2bf(b) << 16);
}
// truncating pack: low16 = bf16(a), high16 = bf16(b), one v_perm_b32
__device__ __forceinline__ uint32_t permpack(float a, float b) {
  return __builtin_amdgcn_perm(__builtin_bit_cast(uint32_t, b),
                               __builtin_bit_cast(uint32_t, a), 0x07060302u);
}

__device__ __forceinline__ void gl2lds16(const void* g, void* l) {
  __builtin_amdgcn_global_load_lds(
      (const __attribute__((address_space(1))) unsigned int*)g,
      (__attribute__((address_space(3))) unsigned int*)l, 16, 0, 0);
}

// ------------- prep: converts + RoPE tables + mask2, one kernel -------------
#define NX_ (1 << 20)
#define NW_ (1 << 18)
#define NROPE_ 65536
__global__ void prep_kernel(const float* __restrict__ X, const float* __restrict__ Wq,
                            const float* __restrict__ Wk, const float* __restrict__ Wv,
                            const float* __restrict__ mask, u16* __restrict__ Xb,
                            u16* __restrict__ Wqb, u16* __restrict__ Wkb,
                            u16* __restrict__ Wvb, float* __restrict__ cos_t,
                            float* __restrict__ sin_t, float* __restrict__ mask2) {
  int i = blockIdx.x * 256 + threadIdx.x;
  if (i < NX_ + 3 * NW_) {
    const float* src;
    u16* dst;
    int off;
    if (i < NX_) {
      src = X; dst = Xb; off = i;
    } else if (i < NX_ + NW_) {
      src = Wq; dst = Wqb; off = i - NX_;
    } else if (i < NX_ + 2 * NW_) {
      src = Wk; dst = Wkb; off = i - NX_ - NW_;
    } else {
      src = Wv; dst = Wvb; off = i - NX_ - 2 * NW_;
    }
    float4 v = ((const float4*)src)[off];
    uint2 packed;
    packed.x = packbf2(v.x, v.y);
    packed.y = packbf2(v.z, v.w);
    ((uint2*)dst)[off] = packed;
  } else if (i < NX_ + 3 * NW_ + NROPE_) {
    int t = i - (NX_ + 3 * NW_);  // 65536 = 2048*32
    int s = t >> 5, j = t & 31;
    float invf = powf(10000.0f, -(float)j * (1.0f / 32.0f));
    float ang = (float)s * invf;
    cos_t[t] = cosf(ang);
    sin_t[t] = sinf(ang);
  } else {
    int t = i - (NX_ + 3 * NW_ + NROPE_);  // 4096 = 2*2048
    mask2[t] = fmaf(mask[t], LOG2E, -MAXC_LOG2);
  }
}

// ---------------- QKV GEMM (R4 structure): X+W dbuf in LDS, 1 barrier/iter ----------------
__global__ __launch_bounds__(256) void qkv_gemm_kernel(
    const u16* __restrict__ X, const u16* __restrict__ Wq, const u16* __restrict__ Wk,
    const u16* __restrict__ Wv, const float* __restrict__ cos_t,
    const float* __restrict__ sin_t, u16* __restrict__ Q, u16* __restrict__ K,
    u16* __restrict__ Vt) {
  __shared__ char smem[65536];  // As[2] @ 0/16K, Bs[2] @ 32K/48K
  int tid = threadIdx.x;
  int lane = tid & 63, wave = tid >> 6;
  int wm = wave >> 1, wn = wave & 1;
  int quad = lane >> 4, l16 = lane & 15;
  int which = blockIdx.x >> 3;
  int nbase = (blockIdx.x & 7) * 128;
  int mbase = blockIdx.y * 128;
  const u16* W = (which == 0) ? Wq : (which == 1) ? Wk : Wv;

#pragma unroll
  for (int it = 0; it < 4; ++it) {
    int i = it * 256 + tid;
    int r = i >> 3, gs = i & 7, gsrc = gs ^ (r & 7);
    gl2lds16(X + (size_t)(mbase + r) * HID_ + gsrc * 8, smem + i * 16);
    gl2lds16(W + (size_t)(nbase + r) * HID_ + gsrc * 8, smem + 32768 + i * 16);
  }

  f32x4 acc[4][4] = {};

  for (int kk = 0; kk < 16; ++kk) {
    char* As = smem + (kk & 1) * 16384;
    char* Bs = smem + 32768 + (kk & 1) * 16384;
    __syncthreads();

    if (kk < 15) {
      int k0n = (kk + 1) * 64;
      char* An = smem + ((kk + 1) & 1) * 16384;
      char* Bn = smem + 32768 + ((kk + 1) & 1) * 16384;
#pragma unroll
      for (int it = 0; it < 4; ++it) {
        int i = it * 256 + tid;
        int r = i >> 3, gs = i & 7, gsrc = gs ^ (r & 7);
        gl2lds16(X + (size_t)(mbase + r) * HID_ + k0n + gsrc * 8, An + i * 16);
        gl2lds16(W + (size_t)(nbase + r) * HID_ + k0n + gsrc * 8, Bn + i * 16);
      }
    }

#pragma unroll
    for (int kh = 0; kh < 2; ++kh) {
      bf16x8 afrag[4], bfrag[4];
#pragma unroll
      for (int i4 = 0; i4 < 4; ++i4) {
        int r = wm * 64 + i4 * 16 + l16;
        int L = r * 8 + ((kh * 4 + quad) ^ (r & 7));
        afrag[i4] = *(const bf16x8*)(As + L * 16);
      }
#pragma unroll
      for (int j4 = 0; j4 < 4; ++j4) {
        int r = wn * 64 + j4 * 16 + l16;
        int L = r * 8 + ((kh * 4 + quad) ^ (r & 7));
        bfrag[j4] = *(const bf16x8*)(Bs + L * 16);
      }
      if (which == 2) {
#pragma unroll
        for (int i4 = 0; i4 < 4; ++i4)
#pragma unroll
          for (int j4 = 0; j4 < 4; ++j4)
            acc[i4][j4] = __builtin_amdgcn_mfma_f32_16x16x32_bf16(afrag[i4], bfrag[j4],
                                                                  acc[i4][j4], 0, 0, 0);
      } else {
#pragma unroll
        for (int i4 = 0; i4 < 4; ++i4)
#pragma unroll
          for (int j4 = 0; j4 < 4; ++j4)
            acc[i4][j4] = __builtin_amdgcn_mfma_f32_16x16x32_bf16(bfrag[j4], afrag[i4],
                                                                  acc[i4][j4], 0, 0, 0);
      }
    }
  }

  if (which == 2) {
#pragma unroll
    for (int i4 = 0; i4 < 4; ++i4)
#pragma unroll
      for (int j4 = 0; j4 < 4; ++j4) {
        int m = mbase + wm * 64 + i4 * 16 + quad * 4;
        int n = nbase + wn * 64 + j4 * 16 + l16;
        int b = m >> 11, s0 = m & 2047;
        int h = n >> 6, d = n & 63;
        uint2 pk;
        pk.x = packbf2(acc[i4][j4][0], acc[i4][j4][1]);
        pk.y = packbf2(acc[i4][j4][2], acc[i4][j4][3]);
        *(uint2*)(Vt + (((size_t)(b * H_ + h)) * D_ + d) * S_ + s0) = pk;
      }
  } else {
    u16* dst = (which == 0) ? Q : K;
#pragma unroll
    for (int i4 = 0; i4 < 4; ++i4)
#pragma unroll
      for (int j4 = 0; j4 < 2; ++j4) {
        int m = mbase + wm * 64 + i4 * 16 + l16;
        int n1 = nbase + wn * 64 + j4 * 16 + quad * 4;
        int b = m >> 11, s = m & 2047;
        int h = n1 >> 6, d1 = n1 & 63;
        float4 c4 = *(const float4*)(cos_t + s * 32 + d1);
        float4 s4 = *(const float4*)(sin_t + s * 32 + d1);
        float y1[4], y2[4];
#pragma unroll
        for (int r = 0; r < 4; ++r) {
          float cr = ((const float*)&c4)[r], sr = ((const float*)&s4)[r];
          float x1 = acc[i4][j4][r], x2 = acc[i4][j4 + 2][r];
          y1[r] = x1 * cr - x2 * sr;
          y2[r] = x2 * cr + x1 * sr;
        }
        size_t base = ((size_t)(b * H_ + h) * S_ + s) * D_;
        uint2 p1, p2;
        p1.x = packbf2(y1[0], y1[1]);
        p1.y = packbf2(y1[2], y1[3]);
        p2.x = packbf2(y2[0], y2[1]);
        p2.y = packbf2(y2[2], y2[3]);
        *(uint2*)(dst + base + d1) = p1;
        *(uint2*)(dst + base + d1 + 32) = p2;
      }
  }
}

// PV for one staged tile: P A-frags (wave-private LDS) x V B-frags, plus l via ones.
__device__ __forceinline__ void pv32(const char* Pw, const char* Vp, int q31, int hf,
                                     const bf16x8& ones, f32x16& o0, f32x16& o1,
                                     f32x16& lacc) {
  int l7 = q31 & 7;
  bf16x8 pf[4];
#pragma unroll
  for (int c = 0; c < 4; ++c) {
    int ch = (2 * c + hf) ^ l7;
    pf[c] = *(const bf16x8*)(Pw + q31 * 128 + ch * 16);
  }
#pragma unroll
  for (int c = 0; c < 4; ++c)
    lacc = __builtin_amdgcn_mfma_f32_32x32x16_bf16(pf[c], ones, lacc, 0, 0, 0);
#pragma unroll
  for (int c = 0; c < 4; ++c) {
    int ch = (2 * c + hf) ^ l7;
    bf16x8 v0 = *(const bf16x8*)(Vp + q31 * 128 + ch * 16);
    bf16x8 v1 = *(const bf16x8*)(Vp + (32 + q31) * 128 + ch * 16);
    o0 = __builtin_amdgcn_mfma_f32_32x32x16_bf16(pf[c], v0, o0, 0, 0, 0);
    o1 = __builtin_amdgcn_mfma_f32_32x32x16_bf16(pf[c], v1, o1, 0, 0, 0);
  }
}

// ---------------- Flash attention: 32x32x16 MFMA, 32 q/wave, 4 waves, 2 blocks/CU ----------
// grid (16, 32). 64-key tiles, triple-buffered K/V, single-buffer wave-private P.
// S^T = K*Q^T: C row=key=(reg&3)+8*(reg>>2)+4*half, col=q=lane&31.
__global__ __launch_bounds__(256, 2) void flash_kernel(
    const u16* __restrict__ Q, const u16* __restrict__ K, const u16* __restrict__ Vt,
    const float* __restrict__ mask2, float* __restrict__ out) {
  __shared__ char smem[65536];  // K/V: 3 bufs @ t*16384 (K@+0, V@+8192). P: @49152 + wave*4096.
  int tid = threadIdx.x, wave = tid >> 6;
  int lane = tid & 63;
  int q31 = lane & 31, hf = lane >> 5, l7 = lane & 7;
  int bh = blockIdx.y, b = bh >> 4, hh = bh & 15;
  int qw = blockIdx.x * 128 + wave * 32;
  char* Pw = smem + 49152 + wave * 4096;
  const float* m2row = mask2 + b * S_;
  const u16* Kbase = K + (size_t)bh * S_ * D_;
  const u16* Vbase = Vt + (size_t)bh * D_ * S_;

  // Q B-operand frags: n=q=q31, k(d) = 16c + 8*hf + j
  bf16x8 qfrag[4];
  {
    const u16* qp = Q + ((size_t)bh * S_ + qw + q31) * D_ + 8 * hf;
#pragma unroll
    for (int c = 0; c < 4; ++c) qfrag[c] = *(const bf16x8*)(qp + 16 * c);
  }
  bf16x8 ones;
#pragma unroll
  for (int j = 0; j < 8; ++j) ones[j] = (short)0x3f80;  // bf16 1.0

  f32x16 o0 = {}, o1 = {}, lacc = {};

  // stage tile 0 into buffer 0 (1024 chunks over 256 threads)
#pragma unroll
  for (int it = 0; it < 2; ++it) {
    int i = it * 256 + tid;
    int r = i >> 3, gs = i & 7, gsrc = gs ^ (r & 7);
    gl2lds16(Kbase + (size_t)r * D_ + gsrc * 8, smem + i * 16);
    gl2lds16(Vbase + (size_t)r * S_ + gsrc * 8, smem + 8192 + i * 16);
  }
  // mask prefetch for kt=0: key = kb*32 + g*8 + hf*4 + r0
  float4 mvt[8];
#pragma unroll
  for (int kb = 0; kb < 2; ++kb)
#pragma unroll
    for (int g = 0; g < 4; ++g)
      mvt[kb * 4 + g] = *(const float4*)(m2row + kb * 32 + g * 8 + hf * 4);

  for (int kt = 0; kt < 32; ++kt) {
    char* Ks = smem + (kt % 3) * 16384;
    __syncthreads();  // staging of tile kt complete

    if (kt < 31) {  // stage tile kt+1 into buf (kt+1)%3
      char* Kn = smem + ((kt + 1) % 3) * 16384;
      char* Vn = Kn + 8192;
      int nb = (kt + 1) * 64;
#pragma unroll
      for (int it = 0; it < 2; ++it) {
        int i = it * 256 + tid;
        int r = i >> 3, gs = i & 7, gsrc = gs ^ (r & 7);
        gl2lds16(Kbase + (size_t)(nb + r) * D_ + gsrc * 8, Kn + i * 16);
        gl2lds16(Vbase + (size_t)r * S_ + nb + gsrc * 8, Vn + i * 16);
      }
    }

    // PV for tile kt-1 (V in buf (kt-1)%3 == (kt+2)%3; P wave-private, in-order)
    if (kt > 0) pv32(Pw, smem + ((kt + 2) % 3) * 16384 + 8192, q31, hf, ones, o0, o1, lacc);

    // S^T = K * Q^T : two 32-key C tiles
    f32x16 s0 = {}, s1 = {};
#pragma unroll
    for (int c = 0; c < 4; ++c) {
      int ch = (2 * c + hf) ^ l7;
      bf16x8 k0 = *(const bf16x8*)(Ks + q31 * 128 + ch * 16);
      bf16x8 k1 = *(const bf16x8*)(Ks + (32 + q31) * 128 + ch * 16);
      s0 = __builtin_amdgcn_mfma_f32_32x32x16_bf16(k0, qfrag[c], s0, 0, 0, 0);
      s1 = __builtin_amdgcn_mfma_f32_32x32x16_bf16(k1, qfrag[c], s1, 0, 0, 0);
    }

    // fixed-max softmax: exp2 + perm-pack; write P(kt) (keys r0..r0+3 per b64 chunk)
#pragma unroll
    for (int kb = 0; kb < 2; ++kb) {
#pragma unroll
      for (int g = 0; g < 4; ++g) {
        float pf4[4];
#pragma unroll
        for (int r0 = 0; r0 < 4; ++r0) {
          float sv = kb ? s1[g * 4 + r0] : s0[g * 4 + r0];
          pf4[r0] = __builtin_amdgcn_exp2f(
              fmaf(sv, SCALE_LOG2, ((const float*)&mvt[kb * 4 + g])[r0]));
        }
        uint2 pk;
        pk.x = permpack(pf4[0], pf4[1]);
        pk.y = permpack(pf4[2], pf4[3]);
        int chunk8 = (8 * kb + 2 * g + hf) ^ (2 * l7);
        *(uint2*)(Pw + q31 * 128 + chunk8 * 8) = pk;
      }
    }

    // mask prefetch for kt+1
    if (kt < 31) {
#pragma unroll
      for (int kb = 0; kb < 2; ++kb)
#pragma unroll
        for (int g = 0; g < 4; ++g)
          mvt[kb * 4 + g] =
              *(const float4*)(m2row + (kt + 1) * 64 + kb * 32 + g * 8 + hf * 4);
    }
  }

  // drain: PV for tile 31 (V in buf 31%3 = 1)
  pv32(Pw, smem + 16384 + 8192, q31, hf, ones, o0, o1, lacc);

  // epilogue: reg = 4g+r0 maps to q = qw + r0 + 8g + 4*hf; lacc rows match o rows
#pragma unroll
  for (int g = 0; g < 4; ++g)
#pragma unroll
    for (int r0 = 0; r0 < 4; ++r0) {
      int reg = g * 4 + r0;
      int q = qw + r0 + 8 * g + 4 * hf;
      float invl = 1.0f / lacc[reg];
      size_t base = (((size_t)b * S_ + q) * H_ + hh) * D_;
      out[base + q31] = o0[reg] * invl;
      out[base + 32 + q31] = o1[reg] * invl;
    }
}

extern "C" void kernel_launch(void* const* d_in, const int* in_sizes, int n_in,
                              void* d_out, int out_size, void* d_ws, size_t ws_size,
                              hipStream_t stream) {
  const float* hid = (const float*)d_in[0];
  const float* mask = (const float*)d_in[1];
  const float* Wq = (const float*)d_in[2];
  const float* Wk = (const float*)d_in[3];
  const float* Wv = (const float*)d_in[4];
  float* out = (float*)d_out;
  char* ws = (char*)d_ws;

  u16* Xbf = (u16*)ws;                              // 8 MB
  u16* Wqb = (u16*)(ws + (8u << 20));               // 2 MB
  u16* Wkb = (u16*)(ws + (10u << 20));              // 2 MB
  u16* Wvb = (u16*)(ws + (12u << 20));              // 2 MB
  u16* Qb = (u16*)(ws + (14u << 20));               // 8 MB (BH,S,D)
  u16* Kb = (u16*)(ws + (22u << 20));               // 8 MB (BH,S,D)
  u16* Vtb = (u16*)(ws + (30u << 20));              // 8 MB (BH,D,S)
  float* cos_t = (float*)(ws + (38u << 20));        // 256 KB
  float* sin_t = (float*)(ws + (38u << 20) + (256u << 10));
  float* mask2 = (float*)(ws + (38u << 20) + (512u << 10));  // 16 KB

  prep_kernel<<<7440, 256, 0, stream>>>(hid, Wq, Wk, Wv, mask, Xbf, Wqb, Wkb, Wvb,
                                        cos_t, sin_t, mask2);
  qkv_gemm_kernel<<<dim3(24, 32), 256, 0, stream>>>(Xbf, Wqb, Wkb, Wvb, cos_t, sin_t,
                                                    Qb, Kb, Vtb);
  flash_kernel<<<dim3(16, 32), 256, 0, stream>>>(Qb, Kb, Vtb, mask2, out);
}